// Round 12
// baseline (261.492 us; speedup 1.0000x reference)
//
#include <hip/hip_runtime.h>
#include <hip/hip_bf16.h>
#include <stdint.h>

#define B_DIM 4096
#define T_DIM 8
#define IN_DIM 1024
#define OUT_DIM 1024
#define R_DIM 32

#define BM 256
#define BN 256
#define BK 64
#define NKT (IN_DIM / BK)   // 16

typedef __bf16 bf16x8 __attribute__((ext_vector_type(8)));
typedef float  f32x4  __attribute__((ext_vector_type(4)));

#define VMCNT(n) asm volatile("s_waitcnt vmcnt(" #n ")" ::: "memory")
#define CFENCE() asm volatile("" ::: "memory")
#define BARRIER() do { CFENCE(); __builtin_amdgcn_s_barrier(); CFENCE(); } while (0)

// ---- helpers --------------------------------------------------------------

// round-to-nearest fp32->bf16, two packed into one u32 (lo in low half)
__device__ __forceinline__ uint32_t pack2_bf16(float a, float b) {
  uint32_t ua = __float_as_uint(a), ub = __float_as_uint(b);
  ua = (ua + 0x7FFFu + ((ua >> 16) & 1u)) >> 16;
  ub = (ub + 0x7FFFu + ((ub >> 16) & 1u)) & 0xFFFF0000u;
  return ua | ub;
}

// async global->LDS, 16B per lane; LDS dest is wave-uniform base + lane*16
__device__ __forceinline__ void gload_lds16(const void* g, void* l) {
  __builtin_amdgcn_global_load_lds(
      (const __attribute__((address_space(1))) void*)(uintptr_t)g,
      (__attribute__((address_space(3))) void*)(uint32_t)(uintptr_t)l,
      16, 0, 0);
}

// stage one 16KB bf16 half-tile (128 of 256 rows, 16-row-interleaved) of a
// K-tile into a 32KB LDS operand region. Linear dest + pre-swizzled source
// (rule 21). [R10-proven conflict-free]
__device__ __forceinline__ void stage_half(const uint16_t* gtile, int ktn,
                                           int half, uint8_t* ldsop,
                                           int wave, int lane) {
#pragma unroll
  for (int j = 0; j < 2; ++j) {
    int s = j * 64 + wave * 8 + (lane >> 3);      // slot 0..127 within half
    int c = lane & 7;                             // 16B chunk (row = 128B)
    int row = (s >> 4) * 32 + half * 16 + (s & 15);
    gload_lds16((const uint8_t*)(gtile + (size_t)row * IN_DIM + ktn * BK) +
                    ((c ^ (s & 7)) << 4),
                ldsop + half * 16384 + j * 8192 + wave * 1024);
  }
}

// fragment reads: slot = (row>>5)*16 + (row&15); chunk = (ks*4+kg) ^ (row&7)
__device__ __forceinline__ bf16x8 lds_frag(const uint8_t* op, int grp,
                                           int par, int ks,
                                           int l15, int kg, int l7) {
  return *(const bf16x8*)(op + par * 16384 + (grp >> 1) * 2048 + l15 * 128 +
                          ((((ks << 2) + kg) ^ l7) << 4));
}

// ---- kernel 1: A1[t][i][k] = sum_j first[t][j] * middle[j][i][k] ----------
__global__ void tt_stage1(const float* __restrict__ first,
                          const float* __restrict__ middle,
                          float* __restrict__ a1) {
  int idx = blockIdx.x * 256 + threadIdx.x;     // t*32768 + i*32 + k
  int t  = idx >> 15;
  int ik = idx & 32767;
  float acc = 0.f;
#pragma unroll
  for (int j = 0; j < R_DIM; ++j)
    acc = fmaf(first[t * R_DIM + j], middle[j * (IN_DIM * R_DIM) + ik], acc);
  a1[idx] = acc;
}

// ---- kernel 2: w_T[t][o][i] = sum_k A1[t][i][k]*task[k][o], bf16 ----------
__global__ __launch_bounds__(256) void tt_stage2(const float* __restrict__ a1,
                                                 const float* __restrict__ task,
                                                 __hip_bfloat16* __restrict__ wT) {
  int bid = blockIdx.x;
  int t  = bid >> 8;
  int ob = (bid >> 4) & 15;
  int ib = bid & 15;
  __shared__ float A1s[64][33];
  __shared__ float Ts[32][64];
  int tid = threadIdx.x;
#pragma unroll
  for (int r = 0; r < 8; ++r) {
    int idx2 = tid + 256 * r;              // 64x32 A1 tile
    int il = idx2 >> 5, k = idx2 & 31;
    A1s[il][k] = a1[t * (IN_DIM * R_DIM) + (ib * 64 + il) * R_DIM + k];
  }
#pragma unroll
  for (int r = 0; r < 8; ++r) {
    int idx2 = tid + 256 * r;              // 32x64 task tile
    int k = idx2 >> 6, ol = idx2 & 63;
    Ts[k][ol] = task[k * OUT_DIM + ob * 64 + ol];
  }
  __syncthreads();
  int il = tid & 63;
  int og = tid >> 6;                        // 0..3
  float acc[16];
#pragma unroll
  for (int r = 0; r < 16; ++r) acc[r] = 0.f;
#pragma unroll
  for (int k = 0; k < 32; ++k) {
    float a = A1s[il][k];
#pragma unroll
    for (int r = 0; r < 16; ++r)
      acc[r] = fmaf(a, Ts[k][og * 16 + r], acc[r]);
  }
#pragma unroll
  for (int r = 0; r < 16; ++r) {
    size_t o = (size_t)ob * 64 + og * 16 + r;
    wT[((size_t)t * OUT_DIM + o) * IN_DIM + ib * 64 + il] = __float2bfloat16(acc[r]);
  }
}

// ---- kernel 3: R10 GEMM + in-loop x->xb cvt via global round-trip ---------
// Each block converts its OWN A-panel K-tile (kt+2) from x fp32 to xb bf16
// (plain loads -> pack -> global_store; 4 sharing blocks write IDENTICAL
// bytes = benign race), then stages kt+1 via the proven gload_lds path.
// Per-thread vmem FIFO per kt (16 ops): P2 issues XL(kt+2)x8 then h0(kt+1)x4;
// P3 VMCNT(4) drains XL (1-phase cover), cvt, ST(kt+2)x4; P4 issues h1x4,
// VMCNT(8) drains h0(kt+1) (2-phase cover, ST+h1 stay flying);
// P1 VMCNT(0) (position-identical to R10) also drains ST before the gloads
// of xb(kt+2) are issued in P2 -> same-block store->load ordering holds.
__global__ __launch_bounds__(512, 2) void tt_gemm(const float* __restrict__ X,
                                                  uint16_t* __restrict__ XB,
                                                  const uint16_t* __restrict__ WT,
                                                  float* __restrict__ O) {
  extern __shared__ uint8_t sm[];
  int bid = blockIdx.x;
  const int t  = bid & 7;                 // task == XCD (round-robin dispatch)
  const int l  = bid >> 3;                // 0..63 within task
  const int mt = l >> 2;                  // 0..15
  const int nt = l & 3;                   // n-fastest: panel L2-shared

  const int tid  = threadIdx.x;
  const int lane = tid & 63;
  const int wave = tid >> 6;              // 0..7
  const int wr = wave >> 2, wc = wave & 3;
  const int wr8 = wr * 8, wc4 = wc * 4;
  const int l15 = lane & 15, l7 = lane & 7, kg = lane >> 4;

  // cvt assignment: thread -> (row_in = tid>>1, kh = tid&1); 128B fp32 ->
  // 64B bf16 per K-tile.
  const int row_in = tid >> 1;
  const int kh = tid & 1;
  const float* xsrc0 =
      X + ((size_t)(mt * BM + row_in) * T_DIM + t) * IN_DIM + kh * 32;
  uint16_t* xdst0 =
      XB + ((size_t)t * B_DIM + mt * BM + row_in) * IN_DIM + kh * 32;

  const uint16_t* gA = XB + ((size_t)t * B_DIM + mt * BM) * IN_DIM;
  const uint16_t* gB = WT + ((size_t)t * OUT_DIM + nt * BN) * IN_DIM;

  uint8_t* bA = sm;            // A: h0 @0, h1 @16384
  uint8_t* bB = sm + 32768;    // B: h0 @0, h1 @16384

  f32x4 acc[8][4] = {};
  bf16x8 afr[4][2], bfr0[2][2], bfr1[2][2];
  float4 xl[8];

  // ---- prologue: cvt K-tiles 0,1 into xb; then stage K-tile 0 (R10 form)
#pragma unroll
  for (int p = 0; p < 2; ++p) {
#pragma unroll
    for (int j = 0; j < 8; ++j)
      xl[j] = *(const float4*)(xsrc0 + p * BK + j * 4);
    VMCNT(0);
#pragma unroll
    for (int j = 0; j < 4; ++j) {
      uint4 o;
      o.x = pack2_bf16(xl[2 * j].x, xl[2 * j].y);
      o.y = pack2_bf16(xl[2 * j].z, xl[2 * j].w);
      o.z = pack2_bf16(xl[2 * j + 1].x, xl[2 * j + 1].y);
      o.w = pack2_bf16(xl[2 * j + 1].z, xl[2 * j + 1].w);
      *(uint4*)(xdst0 + p * BK + j * 8) = o;
    }
  }
  VMCNT(0);                    // stores drained -> xb(0),xb(1) in L2
  BARRIER();                   // visible block-wide
  stage_half(gA, 0, 0, bA, wave, lane);
  stage_half(gB, 0, 0, bB, wave, lane);
  stage_half(gA, 0, 1, bA, wave, lane);
  stage_half(gB, 0, 1, bB, wave, lane);
  VMCNT(4);                    // h0(0) ready; h1(0) still flying
  BARRIER();

  for (int kt = 0; kt < NKT; ++kt) {
    const bool st = (kt + 1) < NKT;       // stage next tile
    const bool cv = (kt + 2) < NKT;       // cvt chain active (kt <= 13)

    // ===== P1: (mp0, np0) — reads h0(kt)
#pragma unroll
    for (int mo = 0; mo < 4; ++mo)
#pragma unroll
      for (int ks = 0; ks < 2; ++ks)
        afr[mo][ks] = lds_frag(bA, wr8 + mo * 2, 0, ks, l15, kg, l7);
#pragma unroll
    for (int no = 0; no < 2; ++no)
#pragma unroll
      for (int ks = 0; ks < 2; ++ks)
        bfr0[no][ks] = lds_frag(bB, wc4 + no * 2, 0, ks, l15, kg, l7);
    VMCNT(0);                  // h1(kt) ready; ST(kt+1) drained (pre-gload)
    BARRIER();
    __builtin_amdgcn_s_setprio(1);
#pragma unroll
    for (int mo = 0; mo < 4; ++mo)
#pragma unroll
      for (int no = 0; no < 2; ++no)
#pragma unroll
        for (int ks = 0; ks < 2; ++ks)
          acc[mo * 2][no * 2] = __builtin_amdgcn_mfma_f32_16x16x32_bf16(
              afr[mo][ks], bfr0[no][ks], acc[mo * 2][no * 2], 0, 0, 0);
    __builtin_amdgcn_s_setprio(0);
    BARRIER();

    // ===== P2: (mp0, np1) — issue XL(kt+2), then stage h0(kt+1)
#pragma unroll
    for (int no = 0; no < 2; ++no)
#pragma unroll
      for (int ks = 0; ks < 2; ++ks)
        bfr1[no][ks] = lds_frag(bB, wc4 + no * 2 + 1, 1, ks, l15, kg, l7);
    if (cv) {
      const float* xs = xsrc0 + (size_t)(kt + 2) * BK;
#pragma unroll
      for (int j = 0; j < 8; ++j)
        xl[j] = *(const float4*)(xs + j * 4);
    }
    if (st) {
      stage_half(gA, kt + 1, 0, bA, wave, lane);
      stage_half(gB, kt + 1, 0, bB, wave, lane);
    }
    BARRIER();
    __builtin_amdgcn_s_setprio(1);
#pragma unroll
    for (int mo = 0; mo < 4; ++mo)
#pragma unroll
      for (int no = 0; no < 2; ++no)
#pragma unroll
        for (int ks = 0; ks < 2; ++ks)
          acc[mo * 2][no * 2 + 1] = __builtin_amdgcn_mfma_f32_16x16x32_bf16(
              afr[mo][ks], bfr1[no][ks], acc[mo * 2][no * 2 + 1], 0, 0, 0);
    __builtin_amdgcn_s_setprio(0);
    BARRIER();

    // ===== P3: (mp1, np0) — drain XL, cvt+store xb(kt+2); bfr0 live from P1
#pragma unroll
    for (int mo = 0; mo < 4; ++mo)
#pragma unroll
      for (int ks = 0; ks < 2; ++ks)
        afr[mo][ks] = lds_frag(bA, wr8 + mo * 2 + 1, 1, ks, l15, kg, l7);
    if (cv) {
      VMCNT(4);                // XL(kt+2)x8 done; h0(kt+1)x4 stays in flight
      uint16_t* xd = xdst0 + (size_t)(kt + 2) * BK;
#pragma unroll
      for (int j = 0; j < 4; ++j) {
        uint4 o;
        o.x = pack2_bf16(xl[2 * j].x, xl[2 * j].y);
        o.y = pack2_bf16(xl[2 * j].z, xl[2 * j].w);
        o.z = pack2_bf16(xl[2 * j + 1].x, xl[2 * j + 1].y);
        o.w = pack2_bf16(xl[2 * j + 1].z, xl[2 * j + 1].w);
        *(uint4*)(xd + j * 8) = o;
      }
    }
    BARRIER();
    __builtin_amdgcn_s_setprio(1);
#pragma unroll
    for (int mo = 0; mo < 4; ++mo)
#pragma unroll
      for (int no = 0; no < 2; ++no)
#pragma unroll
        for (int ks = 0; ks < 2; ++ks)
          acc[mo * 2 + 1][no * 2] = __builtin_amdgcn_mfma_f32_16x16x32_bf16(
              afr[mo][ks], bfr0[no][ks], acc[mo * 2 + 1][no * 2], 0, 0, 0);
    __builtin_amdgcn_s_setprio(0);
    BARRIER();

    // ===== P4: (mp1, np1) — stage h1(kt+1); counted drain of h0(kt+1)
    if (st) {
      stage_half(gA, kt + 1, 1, bA, wave, lane);
      stage_half(gB, kt + 1, 1, bB, wave, lane);
    }
    if (cv) {
      VMCNT(8);                // drain h0(kt+1) (2-phase cover);
                               // ST(kt+2)x4 + h1(kt+1)x4 stay flying
    } else if (st) {
      VMCNT(4);                // kt==14: drain h0(15), keep h1(15)
    }
    BARRIER();
    __builtin_amdgcn_s_setprio(1);
#pragma unroll
    for (int mo = 0; mo < 4; ++mo)
#pragma unroll
      for (int no = 0; no < 2; ++no)
#pragma unroll
        for (int ks = 0; ks < 2; ++ks)
          acc[mo * 2 + 1][no * 2 + 1] = __builtin_amdgcn_mfma_f32_16x16x32_bf16(
              afr[mo][ks], bfr1[no][ks], acc[mo * 2 + 1][no * 2 + 1], 0, 0, 0);
    __builtin_amdgcn_s_setprio(0);
    BARRIER();
  }

  // ---- epilogue: C/D layout col=lane&15, row=(lane>>4)*4+j (m89-verified)
  const int crow0 = mt * BM + wr * 128 + (lane >> 4) * 4;
  const int ccol0 = nt * BN + wc * 64 + (lane & 15);
#pragma unroll
  for (int m = 0; m < 8; ++m) {
#pragma unroll
    for (int j = 0; j < 4; ++j) {
      size_t rowoff =
          ((size_t)(crow0 + m * 16 + j) * T_DIM + t) * OUT_DIM + ccol0;
#pragma unroll
      for (int n = 0; n < 4; ++n)
        O[rowoff + n * 16] = acc[m][n][j];
    }
  }
}

// ---- host ------------------------------------------------------------------
extern "C" void kernel_launch(void* const* d_in, const int* in_sizes, int n_in,
                              void* d_out, int out_size, void* d_ws, size_t ws_size,
                              hipStream_t stream) {
  const float* x      = (const float*)d_in[0];
  const float* first  = (const float*)d_in[1];
  const float* middle = (const float*)d_in[2];
  const float* task   = (const float*)d_in[3];
  float* out = (float*)d_out;

  // ws: a1 fp32 1MB @0; wT bf16 16MB @1MB; xb bf16 64MB @17MB
  float* a1 = (float*)d_ws;
  __hip_bfloat16* wT = (__hip_bfloat16*)((uint8_t*)d_ws + (1u << 20));
  uint16_t* xb = (uint16_t*)((uint8_t*)d_ws + (17u << 20));

  hipFuncSetAttribute((const void*)tt_gemm,
                      hipFuncAttributeMaxDynamicSharedMemorySize, 65536);

  tt_stage1<<<(T_DIM * IN_DIM * R_DIM) / 256, 256, 0, stream>>>(first, middle, a1);
  tt_stage2<<<T_DIM * 16 * 16, 256, 0, stream>>>(a1, task, wT);
  tt_gemm<<<T_DIM * (B_DIM / BM) * (OUT_DIM / BN), 512, 65536, stream>>>(
      x, xb, (const uint16_t*)wT, out);
}

// Round 13
// 260.985 us; speedup vs baseline: 1.0019x; 1.0019x over previous
//
#include <hip/hip_runtime.h>
#include <hip/hip_bf16.h>
#include <stdint.h>

#define B_DIM 4096
#define T_DIM 8
#define IN_DIM 1024
#define OUT_DIM 1024
#define R_DIM 32

#define BM 256
#define BN 256
#define BK 64
#define NKT (IN_DIM / BK)   // 16

typedef __bf16 bf16x8 __attribute__((ext_vector_type(8)));
typedef float  f32x4  __attribute__((ext_vector_type(4)));

#define VMCNT(n) asm volatile("s_waitcnt vmcnt(" #n ")" ::: "memory")
#define CFENCE() asm volatile("" ::: "memory")
#define BARRIER() do { CFENCE(); __builtin_amdgcn_s_barrier(); CFENCE(); } while (0)

// ---- helpers --------------------------------------------------------------

// round-to-nearest fp32->bf16, two packed into one u32 (lo in low half)
__device__ __forceinline__ uint32_t pack2_bf16(float a, float b) {
  uint32_t ua = __float_as_uint(a), ub = __float_as_uint(b);
  ua = (ua + 0x7FFFu + ((ua >> 16) & 1u)) >> 16;
  ub = (ub + 0x7FFFu + ((ub >> 16) & 1u)) & 0xFFFF0000u;
  return ua | ub;
}

// async global->LDS, 16B per lane; LDS dest is wave-uniform base + lane*16
__device__ __forceinline__ void gload_lds16(const void* g, void* l) {
  __builtin_amdgcn_global_load_lds(
      (const __attribute__((address_space(1))) void*)(uintptr_t)g,
      (__attribute__((address_space(3))) void*)(uint32_t)(uintptr_t)l,
      16, 0, 0);
}

// stage one 16KB bf16 half-tile (128 of 256 rows, 16-row-interleaved) of a
// K-tile into a 32KB LDS operand region. Linear dest + pre-swizzled source
// (rule 21). [R10-proven conflict-free]
__device__ __forceinline__ void stage_half(const uint16_t* gtile, int ktn,
                                           int half, uint8_t* ldsop,
                                           int wave, int lane) {
#pragma unroll
  for (int j = 0; j < 2; ++j) {
    int s = j * 64 + wave * 8 + (lane >> 3);      // slot 0..127 within half
    int c = lane & 7;                             // 16B chunk (row = 128B)
    int row = (s >> 4) * 32 + half * 16 + (s & 15);
    gload_lds16((const uint8_t*)(gtile + (size_t)row * IN_DIM + ktn * BK) +
                    ((c ^ (s & 7)) << 4),
                ldsop + half * 16384 + j * 8192 + wave * 1024);
  }
}

// fragment reads: slot = (row>>5)*16 + (row&15); chunk = (ks*4+kg) ^ (row&7)
__device__ __forceinline__ bf16x8 lds_frag(const uint8_t* op, int grp,
                                           int par, int ks,
                                           int l15, int kg, int l7) {
  return *(const bf16x8*)(op + par * 16384 + (grp >> 1) * 2048 + l15 * 128 +
                          ((((ks << 2) + kg) ^ l7) << 4));
}

// ---- kernel 1: A1[t][i][k] = sum_j first[t][j] * middle[j][i][k] ----------
__global__ void tt_stage1(const float* __restrict__ first,
                          const float* __restrict__ middle,
                          float* __restrict__ a1) {
  int idx = blockIdx.x * 256 + threadIdx.x;     // t*32768 + i*32 + k
  int t  = idx >> 15;
  int ik = idx & 32767;
  float acc = 0.f;
#pragma unroll
  for (int j = 0; j < R_DIM; ++j)
    acc = fmaf(first[t * R_DIM + j], middle[j * (IN_DIM * R_DIM) + ik], acc);
  a1[idx] = acc;
}

// ---- kernel 2: w_T[t][o][i] = sum_k A1[t][i][k]*task[k][o], bf16 ----------
__global__ __launch_bounds__(256) void tt_stage2(const float* __restrict__ a1,
                                                 const float* __restrict__ task,
                                                 __hip_bfloat16* __restrict__ wT) {
  int bid = blockIdx.x;
  int t  = bid >> 8;
  int ob = (bid >> 4) & 15;
  int ib = bid & 15;
  __shared__ float A1s[64][33];
  __shared__ float Ts[32][64];
  int tid = threadIdx.x;
#pragma unroll
  for (int r = 0; r < 8; ++r) {
    int idx2 = tid + 256 * r;              // 64x32 A1 tile
    int il = idx2 >> 5, k = idx2 & 31;
    A1s[il][k] = a1[t * (IN_DIM * R_DIM) + (ib * 64 + il) * R_DIM + k];
  }
#pragma unroll
  for (int r = 0; r < 8; ++r) {
    int idx2 = tid + 256 * r;              // 32x64 task tile
    int k = idx2 >> 6, ol = idx2 & 63;
    Ts[k][ol] = task[k * OUT_DIM + ob * 64 + ol];
  }
  __syncthreads();
  int il = tid & 63;
  int og = tid >> 6;                        // 0..3
  float acc[16];
#pragma unroll
  for (int r = 0; r < 16; ++r) acc[r] = 0.f;
#pragma unroll
  for (int k = 0; k < 32; ++k) {
    float a = A1s[il][k];
#pragma unroll
    for (int r = 0; r < 16; ++r)
      acc[r] = fmaf(a, Ts[k][og * 16 + r], acc[r]);
  }
#pragma unroll
  for (int r = 0; r < 16; ++r) {
    size_t o = (size_t)ob * 64 + og * 16 + r;
    wT[((size_t)t * OUT_DIM + o) * IN_DIM + ib * 64 + il] = __float2bfloat16(acc[r]);
  }
}

// ---- kernel 3: R10 GEMM + in-loop x->xb cvt via global round-trip ---------
// Each block converts its OWN A-panel K-tile (kt+2) from x fp32 to xb bf16
// (plain loads -> pack -> global_store; 4 sharing blocks write IDENTICAL
// bytes = benign race), then stages kt+1 via the proven gload_lds path.
// Per-thread vmem FIFO per kt (16 ops): P2 issues XL(kt+2)x8 then h0(kt+1)x4;
// P3 VMCNT(4) drains XL (1-phase cover), cvt, ST(kt+2)x4; P4 issues h1x4,
// VMCNT(8) drains h0(kt+1) (2-phase cover, ST+h1 stay flying);
// P1 VMCNT(0) (position-identical to R10) also drains ST before the gloads
// of xb(kt+2) are issued in P2 -> same-block store->load ordering holds.
__global__ __launch_bounds__(512, 2) void tt_gemm(const float* __restrict__ X,
                                                  uint16_t* __restrict__ XB,
                                                  const uint16_t* __restrict__ WT,
                                                  float* __restrict__ O) {
  extern __shared__ uint8_t sm[];
  int bid = blockIdx.x;
  const int t  = bid & 7;                 // task == XCD (round-robin dispatch)
  const int l  = bid >> 3;                // 0..63 within task
  const int mt = l >> 2;                  // 0..15
  const int nt = l & 3;                   // n-fastest: panel L2-shared

  const int tid  = threadIdx.x;
  const int lane = tid & 63;
  const int wave = tid >> 6;              // 0..7
  const int wr = wave >> 2, wc = wave & 3;
  const int wr8 = wr * 8, wc4 = wc * 4;
  const int l15 = lane & 15, l7 = lane & 7, kg = lane >> 4;

  // cvt assignment: thread -> (row_in = tid>>1, kh = tid&1); 128B fp32 ->
  // 64B bf16 per K-tile.
  const int row_in = tid >> 1;
  const int kh = tid & 1;
  const float* xsrc0 =
      X + ((size_t)(mt * BM + row_in) * T_DIM + t) * IN_DIM + kh * 32;
  uint16_t* xdst0 =
      XB + ((size_t)t * B_DIM + mt * BM + row_in) * IN_DIM + kh * 32;

  const uint16_t* gA = XB + ((size_t)t * B_DIM + mt * BM) * IN_DIM;
  const uint16_t* gB = WT + ((size_t)t * OUT_DIM + nt * BN) * IN_DIM;

  uint8_t* bA = sm;            // A: h0 @0, h1 @16384
  uint8_t* bB = sm + 32768;    // B: h0 @0, h1 @16384

  f32x4 acc[8][4] = {};
  bf16x8 afr[4][2], bfr0[2][2], bfr1[2][2];
  float4 xl[8];

  // ---- prologue: cvt K-tiles 0,1 into xb; then stage K-tile 0 (R10 form)
#pragma unroll
  for (int p = 0; p < 2; ++p) {
#pragma unroll
    for (int j = 0; j < 8; ++j)
      xl[j] = *(const float4*)(xsrc0 + p * BK + j * 4);
    VMCNT(0);
#pragma unroll
    for (int j = 0; j < 4; ++j) {
      uint4 o;
      o.x = pack2_bf16(xl[2 * j].x, xl[2 * j].y);
      o.y = pack2_bf16(xl[2 * j].z, xl[2 * j].w);
      o.z = pack2_bf16(xl[2 * j + 1].x, xl[2 * j + 1].y);
      o.w = pack2_bf16(xl[2 * j + 1].z, xl[2 * j + 1].w);
      *(uint4*)(xdst0 + p * BK + j * 8) = o;
    }
  }
  VMCNT(0);                    // stores drained -> xb(0),xb(1) in L2
  BARRIER();                   // visible block-wide
  stage_half(gA, 0, 0, bA, wave, lane);
  stage_half(gB, 0, 0, bB, wave, lane);
  stage_half(gA, 0, 1, bA, wave, lane);
  stage_half(gB, 0, 1, bB, wave, lane);
  VMCNT(4);                    // h0(0) ready; h1(0) still flying
  BARRIER();

  for (int kt = 0; kt < NKT; ++kt) {
    const bool st = (kt + 1) < NKT;       // stage next tile
    const bool cv = (kt + 2) < NKT;       // cvt chain active (kt <= 13)

    // ===== P1: (mp0, np0) — reads h0(kt)
#pragma unroll
    for (int mo = 0; mo < 4; ++mo)
#pragma unroll
      for (int ks = 0; ks < 2; ++ks)
        afr[mo][ks] = lds_frag(bA, wr8 + mo * 2, 0, ks, l15, kg, l7);
#pragma unroll
    for (int no = 0; no < 2; ++no)
#pragma unroll
      for (int ks = 0; ks < 2; ++ks)
        bfr0[no][ks] = lds_frag(bB, wc4 + no * 2, 0, ks, l15, kg, l7);
    VMCNT(0);                  // h1(kt) ready; ST(kt+1) drained (pre-gload)
    BARRIER();
    __builtin_amdgcn_s_setprio(1);
#pragma unroll
    for (int mo = 0; mo < 4; ++mo)
#pragma unroll
      for (int no = 0; no < 2; ++no)
#pragma unroll
        for (int ks = 0; ks < 2; ++ks)
          acc[mo * 2][no * 2] = __builtin_amdgcn_mfma_f32_16x16x32_bf16(
              afr[mo][ks], bfr0[no][ks], acc[mo * 2][no * 2], 0, 0, 0);
    __builtin_amdgcn_s_setprio(0);
    BARRIER();

    // ===== P2: (mp0, np1) — issue XL(kt+2), then stage h0(kt+1)
#pragma unroll
    for (int no = 0; no < 2; ++no)
#pragma unroll
      for (int ks = 0; ks < 2; ++ks)
        bfr1[no][ks] = lds_frag(bB, wc4 + no * 2 + 1, 1, ks, l15, kg, l7);
    if (cv) {
      const float* xs = xsrc0 + (size_t)(kt + 2) * BK;
#pragma unroll
      for (int j = 0; j < 8; ++j)
        xl[j] = *(const float4*)(xs + j * 4);
    }
    if (st) {
      stage_half(gA, kt + 1, 0, bA, wave, lane);
      stage_half(gB, kt + 1, 0, bB, wave, lane);
    }
    BARRIER();
    __builtin_amdgcn_s_setprio(1);
#pragma unroll
    for (int mo = 0; mo < 4; ++mo)
#pragma unroll
      for (int no = 0; no < 2; ++no)
#pragma unroll
        for (int ks = 0; ks < 2; ++ks)
          acc[mo * 2][no * 2 + 1] = __builtin_amdgcn_mfma_f32_16x16x32_bf16(
              afr[mo][ks], bfr1[no][ks], acc[mo * 2][no * 2 + 1], 0, 0, 0);
    __builtin_amdgcn_s_setprio(0);
    BARRIER();

    // ===== P3: (mp1, np0) — drain XL, cvt+store xb(kt+2); bfr0 live from P1
#pragma unroll
    for (int mo = 0; mo < 4; ++mo)
#pragma unroll
      for (int ks = 0; ks < 2; ++ks)
        afr[mo][ks] = lds_frag(bA, wr8 + mo * 2 + 1, 1, ks, l15, kg, l7);
    if (cv) {
      VMCNT(4);                // XL(kt+2)x8 done; h0(kt+1)x4 stays in flight
      uint16_t* xd = xdst0 + (size_t)(kt + 2) * BK;
#pragma unroll
      for (int j = 0; j < 4; ++j) {
        uint4 o;
        o.x = pack2_bf16(xl[2 * j].x, xl[2 * j].y);
        o.y = pack2_bf16(xl[2 * j].z, xl[2 * j].w);
        o.z = pack2_bf16(xl[2 * j + 1].x, xl[2 * j + 1].y);
        o.w = pack2_bf16(xl[2 * j + 1].z, xl[2 * j + 1].w);
        *(uint4*)(xd + j * 8) = o;
      }
    }
    BARRIER();
    __builtin_amdgcn_s_setprio(1);
#pragma unroll
    for (int mo = 0; mo < 4; ++mo)
#pragma unroll
      for (int no = 0; no < 2; ++no)
#pragma unroll
        for (int ks = 0; ks < 2; ++ks)
          acc[mo * 2 + 1][no * 2] = __builtin_amdgcn_mfma_f32_16x16x32_bf16(
              afr[mo][ks], bfr0[no][ks], acc[mo * 2 + 1][no * 2], 0, 0, 0);
    __builtin_amdgcn_s_setprio(0);
    BARRIER();

    // ===== P4: (mp1, np1) — stage h1(kt+1); counted drain of h0(kt+1)
    if (st) {
      stage_half(gA, kt + 1, 1, bA, wave, lane);
      stage_half(gB, kt + 1, 1, bB, wave, lane);
    }
    if (cv) {
      VMCNT(8);                // drain h0(kt+1) (2-phase cover);
                               // ST(kt+2)x4 + h1(kt+1)x4 stay flying
    } else if (st) {
      VMCNT(4);                // kt==14: drain h0(15), keep h1(15)
    }
    BARRIER();
    __builtin_amdgcn_s_setprio(1);
#pragma unroll
    for (int mo = 0; mo < 4; ++mo)
#pragma unroll
      for (int no = 0; no < 2; ++no)
#pragma unroll
        for (int ks = 0; ks < 2; ++ks)
          acc[mo * 2 + 1][no * 2 + 1] = __builtin_amdgcn_mfma_f32_16x16x32_bf16(
              afr[mo][ks], bfr1[no][ks], acc[mo * 2 + 1][no * 2 + 1], 0, 0, 0);
    __builtin_amdgcn_s_setprio(0);
    BARRIER();
  }

  // ---- epilogue: C/D layout col=lane&15, row=(lane>>4)*4+j (m89-verified)
  const int crow0 = mt * BM + wr * 128 + (lane >> 4) * 4;
  const int ccol0 = nt * BN + wc * 64 + (lane & 15);
#pragma unroll
  for (int m = 0; m < 8; ++m) {
#pragma unroll
    for (int j = 0; j < 4; ++j) {
      size_t rowoff =
          ((size_t)(crow0 + m * 16 + j) * T_DIM + t) * OUT_DIM + ccol0;
#pragma unroll
      for (int n = 0; n < 4; ++n)
        O[rowoff + n * 16] = acc[m][n][j];
    }
  }
}

// ---- host ------------------------------------------------------------------
extern "C" void kernel_launch(void* const* d_in, const int* in_sizes, int n_in,
                              void* d_out, int out_size, void* d_ws, size_t ws_size,
                              hipStream_t stream) {
  const float* x      = (const float*)d_in[0];
  const float* first  = (const float*)d_in[1];
  const float* middle = (const float*)d_in[2];
  const float* task   = (const float*)d_in[3];
  float* out = (float*)d_out;

  // ws: a1 fp32 1MB @0; wT bf16 16MB @1MB; xb bf16 64MB @17MB
  float* a1 = (float*)d_ws;
  __hip_bfloat16* wT = (__hip_bfloat16*)((uint8_t*)d_ws + (1u << 20));
  uint16_t* xb = (uint16_t*)((uint8_t*)d_ws + (17u << 20));

  hipFuncSetAttribute((const void*)tt_gemm,
                      hipFuncAttributeMaxDynamicSharedMemorySize, 65536);

  tt_stage1<<<(T_DIM * IN_DIM * R_DIM) / 256, 256, 0, stream>>>(first, middle, a1);
  tt_stage2<<<T_DIM * 16 * 16, 256, 0, stream>>>(a1, task, wT);
  tt_gemm<<<T_DIM * (B_DIM / BM) * (OUT_DIM / BN), 512, 65536, stream>>>(
      x, xb, (const uint16_t*)wT, out);
}